// Round 2
// baseline (2266.727 us; speedup 1.0000x reference)
//
#include <hip/hip_runtime.h>
#include <cstdint>

// Problem: B=4, N=1024, C=768, H=12, hd=64
// Outputs fp32 concat: out[4,1024,768] then attn[4,12,1024,1024]
#define OUT0_ELEMS 3145728   // 4096*768
#define QKV_F32    3145728   // 48*1024*64 elements per tensor

// ---------------------------------------------------------------------------
// Tiled fp32 GEMM: C[M][O] = A[M][768] @ W[O][768]^T + bias
// BM=BN=128, BK=16, 256 threads, 8x8 micro-tile, XOR-swizzled LDS columns.
// SCATTER=1: qkv epilogue -> Q(*0.125)/K/V in [bh][n][d] layout.
// SCATTER=0: plain C0[m][o] write (proj).
// ---------------------------------------------------------------------------
template<int SCATTER>
__global__ __launch_bounds__(256)
void gemm128(const float* __restrict__ A, const float* __restrict__ W,
             const float* __restrict__ bias,
             float* __restrict__ C0, float* __restrict__ C1, float* __restrict__ C2)
{
    __shared__ float As[16][132];   // col-swizzled: col c stored at c ^ ((c&32)>>3)
    __shared__ float Ws[16][132];
    const int tid = threadIdx.x;
    const int tx = tid & 15;            // col group (8 cols)
    const int ty = tid >> 4;            // row group (8 rows)
    const int m0 = blockIdx.y * 128;
    const int o0 = blockIdx.x * 128;
    const int lr = tid >> 2;            // 0..63 (staging row)
    const int lk = (tid & 3) << 2;      // 0,4,8,12 (staging k)

    const int cs0 = lr ^ ((lr & 32) >> 3);
    const int cs1 = cs0 + 64;

    const float* Ar0 = A + (size_t)(m0 + lr) * 768 + lk;
    const float* Ar1 = Ar0 + (size_t)64 * 768;
    const float* Wr0 = W + (size_t)(o0 + lr) * 768 + lk;
    const float* Wr1 = Wr0 + (size_t)64 * 768;

    const int ab = ty << 3;
    const int ax = (ab & 32) >> 3;
    const int a0i = ab ^ ax, a1i = (ab + 4) ^ ax;
    const int bb = tx << 3;
    const int bx = (bb & 32) >> 3;
    const int b0i = bb ^ bx, b1i = (bb + 4) ^ bx;

    float acc[8][8] = {};

    for (int k0 = 0; k0 < 768; k0 += 16) {
        float4 av0 = *(const float4*)(Ar0 + k0);
        float4 av1 = *(const float4*)(Ar1 + k0);
        float4 wv0 = *(const float4*)(Wr0 + k0);
        float4 wv1 = *(const float4*)(Wr1 + k0);
        __syncthreads();
        As[lk+0][cs0]=av0.x; As[lk+1][cs0]=av0.y; As[lk+2][cs0]=av0.z; As[lk+3][cs0]=av0.w;
        As[lk+0][cs1]=av1.x; As[lk+1][cs1]=av1.y; As[lk+2][cs1]=av1.z; As[lk+3][cs1]=av1.w;
        Ws[lk+0][cs0]=wv0.x; Ws[lk+1][cs0]=wv0.y; Ws[lk+2][cs0]=wv0.z; Ws[lk+3][cs0]=wv0.w;
        Ws[lk+0][cs1]=wv1.x; Ws[lk+1][cs1]=wv1.y; Ws[lk+2][cs1]=wv1.z; Ws[lk+3][cs1]=wv1.w;
        __syncthreads();
        #pragma unroll
        for (int kk = 0; kk < 16; ++kk) {
            float4 aL = *(const float4*)&As[kk][a0i];
            float4 aH = *(const float4*)&As[kk][a1i];
            float4 bL = *(const float4*)&Ws[kk][b0i];
            float4 bH = *(const float4*)&Ws[kk][b1i];
            float a[8] = {aL.x,aL.y,aL.z,aL.w,aH.x,aH.y,aH.z,aH.w};
            float b[8] = {bL.x,bL.y,bL.z,bL.w,bH.x,bH.y,bH.z,bH.w};
            #pragma unroll
            for (int i = 0; i < 8; ++i)
                #pragma unroll
                for (int j = 0; j < 8; ++j)
                    acc[i][j] = fmaf(a[i], b[j], acc[i][j]);
        }
    }

    const float4 bj0 = *(const float4*)(bias + o0 + bb);
    const float4 bj1 = *(const float4*)(bias + o0 + bb + 4);

    if (SCATTER) {
        const int oc   = o0 + bb;
        const int sidx = oc / 768;
        const int rem  = oc - sidx * 768;
        const int h = rem >> 6, d0 = rem & 63;
        const float scale = (sidx == 0) ? 0.125f : 1.0f;
        float* T = (sidx == 0) ? C0 : ((sidx == 1) ? C1 : C2);
        const int b = m0 >> 10;
        float* Tb = T + ((size_t)(b * 12 + h) * 1024) * 64 + d0;
        #pragma unroll
        for (int i = 0; i < 8; ++i) {
            const int n = (m0 & 1023) + (ty << 3) + i;
            float4 r0, r1;
            r0.x=(acc[i][0]+bj0.x)*scale; r0.y=(acc[i][1]+bj0.y)*scale;
            r0.z=(acc[i][2]+bj0.z)*scale; r0.w=(acc[i][3]+bj0.w)*scale;
            r1.x=(acc[i][4]+bj1.x)*scale; r1.y=(acc[i][5]+bj1.y)*scale;
            r1.z=(acc[i][6]+bj1.z)*scale; r1.w=(acc[i][7]+bj1.w)*scale;
            *(float4*)(Tb + (size_t)n * 64)     = r0;
            *(float4*)(Tb + (size_t)n * 64 + 4) = r1;
        }
    } else {
        #pragma unroll
        for (int i = 0; i < 8; ++i) {
            const int m = m0 + (ty << 3) + i;
            float4 r0, r1;
            r0.x=acc[i][0]+bj0.x; r0.y=acc[i][1]+bj0.y;
            r0.z=acc[i][2]+bj0.z; r0.w=acc[i][3]+bj0.w;
            r1.x=acc[i][4]+bj1.x; r1.y=acc[i][5]+bj1.y;
            r1.z=acc[i][6]+bj1.z; r1.w=acc[i][7]+bj1.w;
            *(float4*)(C0 + (size_t)m * 768 + o0 + bb)     = r0;
            *(float4*)(C0 + (size_t)m * 768 + o0 + bb + 4) = r1;
        }
    }
}

// ---------------------------------------------------------------------------
// Scores + softmax + row0 fix + attn write. 8 query rows per block.
// LDS 34 KB -> 4 blocks/CU; __launch_bounds__(256,4) caps VGPR <= 128.
// Softmax: 32 lanes/row, stride-32 elements => every LDS pass is 2-way (free).
// grid = (128 row-tiles, 48 bh), 256 threads.
// ---------------------------------------------------------------------------
__global__ __launch_bounds__(256, 4)
void attn_scores(const float* __restrict__ Q, const float* __restrict__ K,
                 const float* __restrict__ cls_bias, float* __restrict__ attn)
{
    __shared__ float s[8 * 1024];   // 32 KB: 8 score rows
    __shared__ float qs[8 * 64];    // 2 KB: Q tile (pre-scaled by 0.125)
    const int tid = threadIdx.x;
    const int bh  = blockIdx.y;
    const int rt  = blockIdx.x;
    const int q0  = rt << 3;
    const size_t bhoff = (size_t)bh << 16;   // bh * 1024 * 64

    if (tid < 128)
        ((float4*)qs)[tid] = ((const float4*)(Q + bhoff + ((size_t)q0 << 6)))[tid];
    __syncthreads();

    // ---- phase 1: S[q][key] = Q[q] . K[key], key = chunk*256 + tid ----
    const float* Kb = K + bhoff;
    #pragma unroll 1
    for (int chunk = 0; chunk < 4; ++chunk) {
        const int key = (chunk << 8) + tid;
        float4 kreg[16];
        const float4* Kr = (const float4*)(Kb + ((size_t)key << 6));
        #pragma unroll
        for (int j = 0; j < 16; ++j) kreg[j] = Kr[j];
        #pragma unroll
        for (int q = 0; q < 8; ++q) {
            const float4* Qr = (const float4*)(qs + (q << 6));
            float a0 = 0.f, a1 = 0.f, a2 = 0.f, a3 = 0.f;
            #pragma unroll
            for (int j = 0; j < 16; ++j) {
                float4 qv = Qr[j];            // broadcast ds_read_b128
                a0 = fmaf(qv.x, kreg[j].x, a0);
                a1 = fmaf(qv.y, kreg[j].y, a1);
                a2 = fmaf(qv.z, kreg[j].z, a2);
                a3 = fmaf(qv.w, kreg[j].w, a3);
            }
            s[(q << 10) + key] = (a0 + a1) + (a2 + a3);
        }
    }
    __syncthreads();

    // ---- phase 2: softmax, 32 lanes per row (banks: 2-way = free) ----
    {
        const int q = tid >> 5, sub = tid & 31;
        float* row = s + (q << 10);
        float mx = -3.0e38f;
        #pragma unroll 8
        for (int j = 0; j < 32; ++j) mx = fmaxf(mx, row[sub + (j << 5)]);
        #pragma unroll
        for (int off = 16; off; off >>= 1) mx = fmaxf(mx, __shfl_xor(mx, off, 32));
        float sm = 0.f;
        #pragma unroll 8
        for (int j = 0; j < 32; ++j) {
            const int k = sub + (j << 5);
            const float e = __expf(row[k] - mx);
            row[k] = e;
            sm += e;
        }
        #pragma unroll
        for (int off = 16; off; off >>= 1) sm += __shfl_xor(sm, off, 32);
        const float inv = 1.0f / sm;
        #pragma unroll 8
        for (int j = 0; j < 32; ++j) row[sub + (j << 5)] *= inv;
    }
    __syncthreads();

    // ---- row0 fix: global query 0 lives in block rt==0, q-group 0 ----
    if (rt == 0 && tid < 32) {
        const float p0  = s[0];
        const float a00 = fminf(fmaxf(p0 + cls_bias[bh % 12], 0.f), 1.f);
        float actual = 0.f;
        for (int j = 0; j < 32; ++j) {
            const int k = tid + (j << 5);
            if (k) actual += s[k];
        }
        #pragma unroll
        for (int off = 16; off; off >>= 1) actual += __shfl_xor(actual, off, 32);
        const float mp = (1.0f - a00) / (actual + 1e-6f);
        for (int j = 0; j < 32; ++j) {
            const int k = tid + (j << 5);
            s[k] = (k == 0) ? a00 : fminf(fmaxf(s[k] * mp, 0.f), 1.f);
        }
    }
    __syncthreads();

    // ---- phase 3: write attn (output 1), coalesced float4 ----
    {
        float4* dst = (float4*)(attn + ((size_t)bh << 20) + ((size_t)q0 << 10));
        const float4* src = (const float4*)s;
        #pragma unroll
        for (int i = 0; i < 8; ++i)
            dst[tid + (i << 8)] = src[tid + (i << 8)];
    }
}

// ---------------------------------------------------------------------------
// O1 = attn @ V per (b,h): M=1024, K=1024, N=64. Tiled GEMM, 64x64 tile,
// Bk=16, 4x4 micro-tile, P transposed into LDS (stride 68 = 16B-aligned,
// 2-way banks). V read ONCE per block (vs 16x in the old fused kernel).
// grid = (16 m-tiles, 48 bh), 256 threads, 8.4 KB LDS.
// ---------------------------------------------------------------------------
__global__ __launch_bounds__(256)
void pv_gemm(const float* __restrict__ attn, const float* __restrict__ V,
             float* __restrict__ O1)
{
    __shared__ float Pt[16][68];   // [k][m], stride 272 B (17*16)
    __shared__ float Vt[16][64];   // [k][n]
    const int tid = threadIdx.x;
    const int bh  = blockIdx.y;
    const int m0  = blockIdx.x << 6;
    const int b   = bh / 12, h = bh - b * 12;
    const size_t bhoff = (size_t)bh << 16;
    const float* Pg = attn + ((size_t)bh << 20);

    const int pr = tid >> 2;            // 0..63  P stage row
    const int pk = (tid & 3) << 2;      // 0,4,8,12
    const int vk = tid >> 4;            // 0..15  V stage k
    const int vn = (tid & 15) << 2;     // n quad
    const int tx = tid & 15, ty = tid >> 4;

    float acc[4][4] = {};

    for (int k0 = 0; k0 < 1024; k0 += 16) {
        float4 pv4 = *(const float4*)(Pg + (size_t)(m0 + pr) * 1024 + k0 + pk);
        float4 vv4 = *(const float4*)(V + bhoff + (size_t)(k0 + vk) * 64 + vn);
        __syncthreads();
        Pt[pk+0][pr] = pv4.x; Pt[pk+1][pr] = pv4.y;
        Pt[pk+2][pr] = pv4.z; Pt[pk+3][pr] = pv4.w;
        *(float4*)&Vt[vk][vn] = vv4;
        __syncthreads();
        #pragma unroll
        for (int kk = 0; kk < 16; ++kk) {
            float4 a  = *(const float4*)&Pt[kk][ty << 2];
            float4 bv = *(const float4*)&Vt[kk][tx << 2];
            float av[4] = {a.x, a.y, a.z, a.w};
            float bb[4] = {bv.x, bv.y, bv.z, bv.w};
            #pragma unroll
            for (int i = 0; i < 4; ++i)
                #pragma unroll
                for (int j = 0; j < 4; ++j)
                    acc[i][j] = fmaf(av[i], bb[j], acc[i][j]);
        }
    }

    #pragma unroll
    for (int i = 0; i < 4; ++i) {
        float4 r = {acc[i][0], acc[i][1], acc[i][2], acc[i][3]};
        const int m = m0 + (ty << 2) + i;
        *(float4*)(O1 + ((size_t)(b * 1024 + m)) * 768 + (h << 6) + (tx << 2)) = r;
    }
}

extern "C" void kernel_launch(void* const* d_in, const int* in_sizes, int n_in,
                              void* d_out, int out_size, void* d_ws, size_t ws_size,
                              hipStream_t stream) {
    const float* x        = (const float*)d_in[0];
    const float* qkv_w    = (const float*)d_in[1];
    const float* qkv_b    = (const float*)d_in[2];
    const float* proj_w   = (const float*)d_in[3];
    const float* proj_b   = (const float*)d_in[4];
    const float* cls_bias = (const float*)d_in[5];

    float* out  = (float*)d_out;
    float* attn = out + OUT0_ELEMS;

    float* ws = (float*)d_ws;
    float* Q  = ws;                       // 12.6 MB (pre-scaled by 0.125)
    float* K  = Q  + (size_t)QKV_F32;     // 12.6 MB
    float* V  = K  + (size_t)QKV_F32;     // 12.6 MB
    float* O1 = V  + (size_t)QKV_F32;     // 12.6 MB

    // 1) qkv = x @ qkv_w.T + qkv_b -> Q(scaled)/K/V
    gemm128<1><<<dim3(18, 32), 256, 0, stream>>>(x, qkv_w, qkv_b, Q, K, V);
    // 2) attn = row0-fixed softmax(Q K^T)  (output 1)
    attn_scores<<<dim3(128, 48), 256, 0, stream>>>(Q, K, cls_bias, attn);
    // 3) O1 = attn @ V  (reads the just-written attn, L3-resident)
    pv_gemm<<<dim3(16, 48), 256, 0, stream>>>(attn, V, O1);
    // 4) out = O1 @ proj_w.T + proj_b  (output 0)
    gemm128<0><<<dim3(6, 32), 256, 0, stream>>>(O1, proj_w, proj_b, out, nullptr, nullptr);
}

// Round 3
// 1045.901 us; speedup vs baseline: 2.1672x; 2.1672x over previous
//
#include <hip/hip_runtime.h>
#include <cstdint>

// Problem: B=4, N=1024, C=768, H=12, hd=64
// Outputs fp32 concat: out[4,1024,768] then attn[4,12,1024,1024]
#define OUT0_ELEMS 3145728   // 4096*768
#define QKV_F32    3145728   // 48*1024*64 elements per tensor

// ---------------------------------------------------------------------------
// Tiled fp32 GEMM: C[M][O] = A[M][768] @ W[O][768]^T + bias
// BM=BN=128, BK=16, 256 threads, 8x8 micro-tile, XOR-swizzled LDS columns.
// SCATTER=1: qkv epilogue -> Q(*0.125)/K/V in [bh][n][d] layout.
// SCATTER=0: plain C0[m][o] write (proj).
// ---------------------------------------------------------------------------
template<int SCATTER>
__global__ __launch_bounds__(256)
void gemm128(const float* __restrict__ A, const float* __restrict__ W,
             const float* __restrict__ bias,
             float* __restrict__ C0, float* __restrict__ C1, float* __restrict__ C2)
{
    __shared__ float As[16][132];   // col-swizzled: col c stored at c ^ ((c&32)>>3)
    __shared__ float Ws[16][132];
    const int tid = threadIdx.x;
    const int tx = tid & 15;            // col group (8 cols)
    const int ty = tid >> 4;            // row group (8 rows)
    const int m0 = blockIdx.y * 128;
    const int o0 = blockIdx.x * 128;
    const int lr = tid >> 2;            // 0..63 (staging row)
    const int lk = (tid & 3) << 2;      // 0,4,8,12 (staging k)

    const int cs0 = lr ^ ((lr & 32) >> 3);
    const int cs1 = cs0 + 64;

    const float* Ar0 = A + (size_t)(m0 + lr) * 768 + lk;
    const float* Ar1 = Ar0 + (size_t)64 * 768;
    const float* Wr0 = W + (size_t)(o0 + lr) * 768 + lk;
    const float* Wr1 = Wr0 + (size_t)64 * 768;

    const int ab = ty << 3;
    const int ax = (ab & 32) >> 3;
    const int a0i = ab ^ ax, a1i = (ab + 4) ^ ax;
    const int bb = tx << 3;
    const int bx = (bb & 32) >> 3;
    const int b0i = bb ^ bx, b1i = (bb + 4) ^ bx;

    float acc[8][8] = {};

    for (int k0 = 0; k0 < 768; k0 += 16) {
        float4 av0 = *(const float4*)(Ar0 + k0);
        float4 av1 = *(const float4*)(Ar1 + k0);
        float4 wv0 = *(const float4*)(Wr0 + k0);
        float4 wv1 = *(const float4*)(Wr1 + k0);
        __syncthreads();
        As[lk+0][cs0]=av0.x; As[lk+1][cs0]=av0.y; As[lk+2][cs0]=av0.z; As[lk+3][cs0]=av0.w;
        As[lk+0][cs1]=av1.x; As[lk+1][cs1]=av1.y; As[lk+2][cs1]=av1.z; As[lk+3][cs1]=av1.w;
        Ws[lk+0][cs0]=wv0.x; Ws[lk+1][cs0]=wv0.y; Ws[lk+2][cs0]=wv0.z; Ws[lk+3][cs0]=wv0.w;
        Ws[lk+0][cs1]=wv1.x; Ws[lk+1][cs1]=wv1.y; Ws[lk+2][cs1]=wv1.z; Ws[lk+3][cs1]=wv1.w;
        __syncthreads();
        #pragma unroll
        for (int kk = 0; kk < 16; ++kk) {
            float4 aL = *(const float4*)&As[kk][a0i];
            float4 aH = *(const float4*)&As[kk][a1i];
            float4 bL = *(const float4*)&Ws[kk][b0i];
            float4 bH = *(const float4*)&Ws[kk][b1i];
            float a[8] = {aL.x,aL.y,aL.z,aL.w,aH.x,aH.y,aH.z,aH.w};
            float b[8] = {bL.x,bL.y,bL.z,bL.w,bH.x,bH.y,bH.z,bH.w};
            #pragma unroll
            for (int i = 0; i < 8; ++i)
                #pragma unroll
                for (int j = 0; j < 8; ++j)
                    acc[i][j] = fmaf(a[i], b[j], acc[i][j]);
        }
    }

    const float4 bj0 = *(const float4*)(bias + o0 + bb);
    const float4 bj1 = *(const float4*)(bias + o0 + bb + 4);

    if (SCATTER) {
        const int oc   = o0 + bb;
        const int sidx = oc / 768;
        const int rem  = oc - sidx * 768;
        const int h = rem >> 6, d0 = rem & 63;
        const float scale = (sidx == 0) ? 0.125f : 1.0f;
        float* T = (sidx == 0) ? C0 : ((sidx == 1) ? C1 : C2);
        const int b = m0 >> 10;
        float* Tb = T + ((size_t)(b * 12 + h) * 1024) * 64 + d0;
        #pragma unroll
        for (int i = 0; i < 8; ++i) {
            const int n = (m0 & 1023) + (ty << 3) + i;
            float4 r0, r1;
            r0.x=(acc[i][0]+bj0.x)*scale; r0.y=(acc[i][1]+bj0.y)*scale;
            r0.z=(acc[i][2]+bj0.z)*scale; r0.w=(acc[i][3]+bj0.w)*scale;
            r1.x=(acc[i][4]+bj1.x)*scale; r1.y=(acc[i][5]+bj1.y)*scale;
            r1.z=(acc[i][6]+bj1.z)*scale; r1.w=(acc[i][7]+bj1.w)*scale;
            *(float4*)(Tb + (size_t)n * 64)     = r0;
            *(float4*)(Tb + (size_t)n * 64 + 4) = r1;
        }
    } else {
        #pragma unroll
        for (int i = 0; i < 8; ++i) {
            const int m = m0 + (ty << 3) + i;
            float4 r0, r1;
            r0.x=acc[i][0]+bj0.x; r0.y=acc[i][1]+bj0.y;
            r0.z=acc[i][2]+bj0.z; r0.w=acc[i][3]+bj0.w;
            r1.x=acc[i][4]+bj1.x; r1.y=acc[i][5]+bj1.y;
            r1.z=acc[i][6]+bj1.z; r1.w=acc[i][7]+bj1.w;
            *(float4*)(C0 + (size_t)m * 768 + o0 + bb)     = r0;
            *(float4*)(C0 + (size_t)m * 768 + o0 + bb + 4) = r1;
        }
    }
}

// ---------------------------------------------------------------------------
// Scores + softmax + row0 fix + attn write. 8 query rows per block.
// LDS 34 KB; plain __launch_bounds__(256) (the (256,4) hint forced VGPR=64
// and spilled kreg to scratch -> 4.6 GB HBM traffic, round-2 regression).
// K registers split into two 8xfloat4 halves so worst-case live set ~<90 VGPR.
// Softmax: 32 lanes/row, stride-32 elements => every LDS pass is 2-way (free).
// grid = (128 row-tiles, 48 bh), 256 threads.
// ---------------------------------------------------------------------------
__global__ __launch_bounds__(256)
void attn_scores(const float* __restrict__ Q, const float* __restrict__ K,
                 const float* __restrict__ cls_bias, float* __restrict__ attn)
{
    __shared__ float s[8 * 1024];   // 32 KB: 8 score rows
    __shared__ float qs[8 * 64];    // 2 KB: Q tile (pre-scaled by 0.125)
    const int tid = threadIdx.x;
    const int bh  = blockIdx.y;
    const int rt  = blockIdx.x;
    const int q0  = rt << 3;
    const size_t bhoff = (size_t)bh << 16;   // bh * 1024 * 64

    if (tid < 128)
        ((float4*)qs)[tid] = ((const float4*)(Q + bhoff + ((size_t)q0 << 6)))[tid];
    __syncthreads();

    // ---- phase 1: S[q][key] = Q[q] . K[key], key = chunk*256 + tid ----
    const float* Kb = K + bhoff;
    #pragma unroll 1
    for (int chunk = 0; chunk < 4; ++chunk) {
        const int key = (chunk << 8) + tid;
        const float4* Kr = (const float4*)(Kb + ((size_t)key << 6));
        float accq[8] = {};
        #pragma unroll
        for (int half = 0; half < 2; ++half) {
            float4 kreg[8];                       // 32 VGPRs live (not 64)
            #pragma unroll
            for (int j = 0; j < 8; ++j) kreg[j] = Kr[(half << 3) + j];
            #pragma unroll
            for (int q = 0; q < 8; ++q) {
                const float4* Qr = (const float4*)(qs + (q << 6)) + (half << 3);
                float a0 = 0.f, a1 = 0.f, a2 = 0.f, a3 = 0.f;
                #pragma unroll
                for (int j = 0; j < 8; ++j) {
                    float4 qv = Qr[j];            // broadcast ds_read_b128
                    a0 = fmaf(qv.x, kreg[j].x, a0);
                    a1 = fmaf(qv.y, kreg[j].y, a1);
                    a2 = fmaf(qv.z, kreg[j].z, a2);
                    a3 = fmaf(qv.w, kreg[j].w, a3);
                }
                accq[q] += (a0 + a1) + (a2 + a3);
            }
        }
        #pragma unroll
        for (int q = 0; q < 8; ++q) s[(q << 10) + key] = accq[q];
    }
    __syncthreads();

    // ---- phase 2: softmax, 32 lanes per row (banks: 2-way = free) ----
    {
        const int q = tid >> 5, sub = tid & 31;
        float* row = s + (q << 10);
        float mx = -3.0e38f;
        #pragma unroll 8
        for (int j = 0; j < 32; ++j) mx = fmaxf(mx, row[sub + (j << 5)]);
        #pragma unroll
        for (int off = 16; off; off >>= 1) mx = fmaxf(mx, __shfl_xor(mx, off, 32));
        float sm = 0.f;
        #pragma unroll 8
        for (int j = 0; j < 32; ++j) {
            const int k = sub + (j << 5);
            const float e = __expf(row[k] - mx);
            row[k] = e;
            sm += e;
        }
        #pragma unroll
        for (int off = 16; off; off >>= 1) sm += __shfl_xor(sm, off, 32);
        const float inv = 1.0f / sm;
        #pragma unroll 8
        for (int j = 0; j < 32; ++j) row[sub + (j << 5)] *= inv;
    }
    __syncthreads();

    // ---- row0 fix: global query 0 lives in block rt==0, q-group 0 ----
    if (rt == 0 && tid < 32) {
        const float p0  = s[0];
        const float a00 = fminf(fmaxf(p0 + cls_bias[bh % 12], 0.f), 1.f);
        float actual = 0.f;
        for (int j = 0; j < 32; ++j) {
            const int k = tid + (j << 5);
            if (k) actual += s[k];
        }
        #pragma unroll
        for (int off = 16; off; off >>= 1) actual += __shfl_xor(actual, off, 32);
        const float mp = (1.0f - a00) / (actual + 1e-6f);
        for (int j = 0; j < 32; ++j) {
            const int k = tid + (j << 5);
            s[k] = (k == 0) ? a00 : fminf(fmaxf(s[k] * mp, 0.f), 1.f);
        }
    }
    __syncthreads();

    // ---- phase 3: write attn (output 1), coalesced float4 ----
    {
        float4* dst = (float4*)(attn + ((size_t)bh << 20) + ((size_t)q0 << 10));
        const float4* src = (const float4*)s;
        #pragma unroll
        for (int i = 0; i < 8; ++i)
            dst[tid + (i << 8)] = src[tid + (i << 8)];
    }
}

// ---------------------------------------------------------------------------
// O1 = attn @ V per (b,h): M=1024, K=1024, N=64. Tiled GEMM, 64x64 tile,
// Bk=16, 4x4 micro-tile, P transposed into LDS (stride 68 = 16B-aligned,
// 2-way banks). V read ONCE per block.
// grid = (16 m-tiles, 48 bh), 256 threads, 8.4 KB LDS.
// ---------------------------------------------------------------------------
__global__ __launch_bounds__(256)
void pv_gemm(const float* __restrict__ attn, const float* __restrict__ V,
             float* __restrict__ O1)
{
    __shared__ float Pt[16][68];   // [k][m], stride 272 B (17*16)
    __shared__ float Vt[16][64];   // [k][n]
    const int tid = threadIdx.x;
    const int bh  = blockIdx.y;
    const int m0  = blockIdx.x << 6;
    const int b   = bh / 12, h = bh - b * 12;
    const size_t bhoff = (size_t)bh << 16;
    const float* Pg = attn + ((size_t)bh << 20);

    const int pr = tid >> 2;            // 0..63  P stage row
    const int pk = (tid & 3) << 2;      // 0,4,8,12
    const int vk = tid >> 4;            // 0..15  V stage k
    const int vn = (tid & 15) << 2;     // n quad
    const int tx = tid & 15, ty = tid >> 4;

    float acc[4][4] = {};

    for (int k0 = 0; k0 < 1024; k0 += 16) {
        float4 pv4 = *(const float4*)(Pg + (size_t)(m0 + pr) * 1024 + k0 + pk);
        float4 vv4 = *(const float4*)(V + bhoff + (size_t)(k0 + vk) * 64 + vn);
        __syncthreads();
        Pt[pk+0][pr] = pv4.x; Pt[pk+1][pr] = pv4.y;
        Pt[pk+2][pr] = pv4.z; Pt[pk+3][pr] = pv4.w;
        *(float4*)&Vt[vk][vn] = vv4;
        __syncthreads();
        #pragma unroll
        for (int kk = 0; kk < 16; ++kk) {
            float4 a  = *(const float4*)&Pt[kk][ty << 2];
            float4 bv = *(const float4*)&Vt[kk][tx << 2];
            float av[4] = {a.x, a.y, a.z, a.w};
            float bb[4] = {bv.x, bv.y, bv.z, bv.w};
            #pragma unroll
            for (int i = 0; i < 4; ++i)
                #pragma unroll
                for (int j = 0; j < 4; ++j)
                    acc[i][j] = fmaf(av[i], bb[j], acc[i][j]);
        }
    }

    #pragma unroll
    for (int i = 0; i < 4; ++i) {
        float4 r = {acc[i][0], acc[i][1], acc[i][2], acc[i][3]};
        const int m = m0 + (ty << 2) + i;
        *(float4*)(O1 + ((size_t)(b * 1024 + m)) * 768 + (h << 6) + (tx << 2)) = r;
    }
}

extern "C" void kernel_launch(void* const* d_in, const int* in_sizes, int n_in,
                              void* d_out, int out_size, void* d_ws, size_t ws_size,
                              hipStream_t stream) {
    const float* x        = (const float*)d_in[0];
    const float* qkv_w    = (const float*)d_in[1];
    const float* qkv_b    = (const float*)d_in[2];
    const float* proj_w   = (const float*)d_in[3];
    const float* proj_b   = (const float*)d_in[4];
    const float* cls_bias = (const float*)d_in[5];

    float* out  = (float*)d_out;
    float* attn = out + OUT0_ELEMS;

    float* ws = (float*)d_ws;
    float* Q  = ws;                       // 12.6 MB (pre-scaled by 0.125)
    float* K  = Q  + (size_t)QKV_F32;     // 12.6 MB
    float* V  = K  + (size_t)QKV_F32;     // 12.6 MB
    float* O1 = V  + (size_t)QKV_F32;     // 12.6 MB

    // 1) qkv = x @ qkv_w.T + qkv_b -> Q(scaled)/K/V
    gemm128<1><<<dim3(18, 32), 256, 0, stream>>>(x, qkv_w, qkv_b, Q, K, V);
    // 2) attn = row0-fixed softmax(Q K^T)  (output 1)
    attn_scores<<<dim3(128, 48), 256, 0, stream>>>(Q, K, cls_bias, attn);
    // 3) O1 = attn @ V  (reads the just-written attn, L3-resident)
    pv_gemm<<<dim3(16, 48), 256, 0, stream>>>(attn, V, O1);
    // 4) out = O1 @ proj_w.T + proj_b  (output 0)
    gemm128<0><<<dim3(6, 32), 256, 0, stream>>>(O1, proj_w, proj_b, out, nullptr, nullptr);
}

// Round 4
// 824.841 us; speedup vs baseline: 2.7481x; 1.2680x over previous
//
#include <hip/hip_runtime.h>
#include <cstdint>

// Problem: B=4, N=1024, C=768, H=12, hd=64
// Outputs fp32 concat: out[4,1024,768] then attn[4,12,1024,1024]
#define OUT0_ELEMS 3145728   // 4096*768
#define QKV_F32    3145728   // 48*1024*64 elements per tensor

// ---------------------------------------------------------------------------
// Tiled fp32 GEMM: C[M][O] = A[M][768] @ W[O][768]^T + bias
// BM=BN=128, BK=16, 256 threads, 8x8 micro-tile, XOR-swizzled LDS columns.
// SCATTER=1: qkv epilogue -> Q(*0.125)/K/V in [bh][n][d] layout.
// SCATTER=0: plain C0[m][o] write (proj).
// ---------------------------------------------------------------------------
template<int SCATTER>
__global__ __launch_bounds__(256)
void gemm128(const float* __restrict__ A, const float* __restrict__ W,
             const float* __restrict__ bias,
             float* __restrict__ C0, float* __restrict__ C1, float* __restrict__ C2)
{
    __shared__ float As[16][132];   // col-swizzled: col c stored at c ^ ((c&32)>>3)
    __shared__ float Ws[16][132];
    const int tid = threadIdx.x;
    const int tx = tid & 15;            // col group (8 cols)
    const int ty = tid >> 4;            // row group (8 rows)
    const int m0 = blockIdx.y * 128;
    const int o0 = blockIdx.x * 128;
    const int lr = tid >> 2;            // 0..63 (staging row)
    const int lk = (tid & 3) << 2;      // 0,4,8,12 (staging k)

    const int cs0 = lr ^ ((lr & 32) >> 3);
    const int cs1 = cs0 + 64;

    const float* Ar0 = A + (size_t)(m0 + lr) * 768 + lk;
    const float* Ar1 = Ar0 + (size_t)64 * 768;
    const float* Wr0 = W + (size_t)(o0 + lr) * 768 + lk;
    const float* Wr1 = Wr0 + (size_t)64 * 768;

    const int ab = ty << 3;
    const int ax = (ab & 32) >> 3;
    const int a0i = ab ^ ax, a1i = (ab + 4) ^ ax;
    const int bb = tx << 3;
    const int bx = (bb & 32) >> 3;
    const int b0i = bb ^ bx, b1i = (bb + 4) ^ bx;

    float acc[8][8] = {};

    for (int k0 = 0; k0 < 768; k0 += 16) {
        float4 av0 = *(const float4*)(Ar0 + k0);
        float4 av1 = *(const float4*)(Ar1 + k0);
        float4 wv0 = *(const float4*)(Wr0 + k0);
        float4 wv1 = *(const float4*)(Wr1 + k0);
        __syncthreads();
        As[lk+0][cs0]=av0.x; As[lk+1][cs0]=av0.y; As[lk+2][cs0]=av0.z; As[lk+3][cs0]=av0.w;
        As[lk+0][cs1]=av1.x; As[lk+1][cs1]=av1.y; As[lk+2][cs1]=av1.z; As[lk+3][cs1]=av1.w;
        Ws[lk+0][cs0]=wv0.x; Ws[lk+1][cs0]=wv0.y; Ws[lk+2][cs0]=wv0.z; Ws[lk+3][cs0]=wv0.w;
        Ws[lk+0][cs1]=wv1.x; Ws[lk+1][cs1]=wv1.y; Ws[lk+2][cs1]=wv1.z; Ws[lk+3][cs1]=wv1.w;
        __syncthreads();
        #pragma unroll
        for (int kk = 0; kk < 16; ++kk) {
            float4 aL = *(const float4*)&As[kk][a0i];
            float4 aH = *(const float4*)&As[kk][a1i];
            float4 bL = *(const float4*)&Ws[kk][b0i];
            float4 bH = *(const float4*)&Ws[kk][b1i];
            float a[8] = {aL.x,aL.y,aL.z,aL.w,aH.x,aH.y,aH.z,aH.w};
            float b[8] = {bL.x,bL.y,bL.z,bL.w,bH.x,bH.y,bH.z,bH.w};
            #pragma unroll
            for (int i = 0; i < 8; ++i)
                #pragma unroll
                for (int j = 0; j < 8; ++j)
                    acc[i][j] = fmaf(a[i], b[j], acc[i][j]);
        }
    }

    const float4 bj0 = *(const float4*)(bias + o0 + bb);
    const float4 bj1 = *(const float4*)(bias + o0 + bb + 4);

    if (SCATTER) {
        const int oc   = o0 + bb;
        const int sidx = oc / 768;
        const int rem  = oc - sidx * 768;
        const int h = rem >> 6, d0 = rem & 63;
        const float scale = (sidx == 0) ? 0.125f : 1.0f;
        float* T = (sidx == 0) ? C0 : ((sidx == 1) ? C1 : C2);
        const int b = m0 >> 10;
        float* Tb = T + ((size_t)(b * 12 + h) * 1024) * 64 + d0;
        #pragma unroll
        for (int i = 0; i < 8; ++i) {
            const int n = (m0 & 1023) + (ty << 3) + i;
            float4 r0, r1;
            r0.x=(acc[i][0]+bj0.x)*scale; r0.y=(acc[i][1]+bj0.y)*scale;
            r0.z=(acc[i][2]+bj0.z)*scale; r0.w=(acc[i][3]+bj0.w)*scale;
            r1.x=(acc[i][4]+bj1.x)*scale; r1.y=(acc[i][5]+bj1.y)*scale;
            r1.z=(acc[i][6]+bj1.z)*scale; r1.w=(acc[i][7]+bj1.w)*scale;
            *(float4*)(Tb + (size_t)n * 64)     = r0;
            *(float4*)(Tb + (size_t)n * 64 + 4) = r1;
        }
    } else {
        #pragma unroll
        for (int i = 0; i < 8; ++i) {
            const int m = m0 + (ty << 3) + i;
            float4 r0, r1;
            r0.x=acc[i][0]+bj0.x; r0.y=acc[i][1]+bj0.y;
            r0.z=acc[i][2]+bj0.z; r0.w=acc[i][3]+bj0.w;
            r1.x=acc[i][4]+bj1.x; r1.y=acc[i][5]+bj1.y;
            r1.z=acc[i][6]+bj1.z; r1.w=acc[i][7]+bj1.w;
            *(float4*)(C0 + (size_t)m * 768 + o0 + bb)     = r0;
            *(float4*)(C0 + (size_t)m * 768 + o0 + bb + 4) = r1;
        }
    }
}

// ---------------------------------------------------------------------------
// Scores + softmax + row0 fix + attn write. 16 query rows per block.
// Phase 1 register-blocked: each thread owns 4 keys (stride 256), acc[16][4]
// in registers; one Q ds_read_b128 feeds 4 keys (ds:FMA = 1:16, was 1:4).
// K loads: per-lane sequential row walk with 1-deep manual prefetch.
// Softmax: 16 lanes/row, (j+q) rotation keeps LDS banks 2-way (free).
// grid = (64 row-tiles, 48 bh), 256 threads, 68 KB LDS (2 blocks/CU).
// ---------------------------------------------------------------------------
__global__ __launch_bounds__(256)
void attn_scores(const float* __restrict__ Q, const float* __restrict__ K,
                 const float* __restrict__ cls_bias, float* __restrict__ attn)
{
    __shared__ float s[16 * 1024];   // 64 KB: 16 score rows
    __shared__ float qs[16 * 64];    // 4 KB: Q tile (pre-scaled by 0.125)
    const int tid = threadIdx.x;
    const int bh  = blockIdx.y;
    const int rt  = blockIdx.x;
    const int q0  = rt << 4;
    const size_t bhoff = (size_t)bh << 16;   // bh * 1024 * 64

    ((float4*)qs)[tid] = ((const float4*)(Q + bhoff + ((size_t)q0 << 6)))[tid];
    __syncthreads();

    // ---- phase 1: acc[q][j] = Q[q] . K[j*256+tid], register-resident ----
    {
        const float* Kb = K + bhoff;
        const float* Kr0 = Kb + ((size_t)(tid      ) << 6);
        const float* Kr1 = Kb + ((size_t)(tid + 256) << 6);
        const float* Kr2 = Kb + ((size_t)(tid + 512) << 6);
        const float* Kr3 = Kb + ((size_t)(tid + 768) << 6);

        float acc[16][4] = {};
        float4 kf0 = *(const float4*)(Kr0);
        float4 kf1 = *(const float4*)(Kr1);
        float4 kf2 = *(const float4*)(Kr2);
        float4 kf3 = *(const float4*)(Kr3);

        #pragma unroll 1
        for (int db = 0; db < 16; ++db) {
            const int dn = (db < 15) ? (db + 1) << 2 : 15 << 2;  // clamped prefetch
            float4 kn0 = *(const float4*)(Kr0 + dn);
            float4 kn1 = *(const float4*)(Kr1 + dn);
            float4 kn2 = *(const float4*)(Kr2 + dn);
            float4 kn3 = *(const float4*)(Kr3 + dn);
            #pragma unroll
            for (int q = 0; q < 16; ++q) {
                float4 qv = *(const float4*)(qs + (q << 6) + (db << 2)); // broadcast
                acc[q][0] = fmaf(qv.x, kf0.x, acc[q][0]);
                acc[q][0] = fmaf(qv.y, kf0.y, acc[q][0]);
                acc[q][0] = fmaf(qv.z, kf0.z, acc[q][0]);
                acc[q][0] = fmaf(qv.w, kf0.w, acc[q][0]);
                acc[q][1] = fmaf(qv.x, kf1.x, acc[q][1]);
                acc[q][1] = fmaf(qv.y, kf1.y, acc[q][1]);
                acc[q][1] = fmaf(qv.z, kf1.z, acc[q][1]);
                acc[q][1] = fmaf(qv.w, kf1.w, acc[q][1]);
                acc[q][2] = fmaf(qv.x, kf2.x, acc[q][2]);
                acc[q][2] = fmaf(qv.y, kf2.y, acc[q][2]);
                acc[q][2] = fmaf(qv.z, kf2.z, acc[q][2]);
                acc[q][2] = fmaf(qv.w, kf2.w, acc[q][2]);
                acc[q][3] = fmaf(qv.x, kf3.x, acc[q][3]);
                acc[q][3] = fmaf(qv.y, kf3.y, acc[q][3]);
                acc[q][3] = fmaf(qv.z, kf3.z, acc[q][3]);
                acc[q][3] = fmaf(qv.w, kf3.w, acc[q][3]);
            }
            kf0 = kn0; kf1 = kn1; kf2 = kn2; kf3 = kn3;
        }

        #pragma unroll
        for (int q = 0; q < 16; ++q) {
            s[(q << 10) +         tid] = acc[q][0];
            s[(q << 10) +  256 +  tid] = acc[q][1];
            s[(q << 10) +  512 +  tid] = acc[q][2];
            s[(q << 10) +  768 +  tid] = acc[q][3];
        }
    }
    __syncthreads();

    // ---- phase 2: softmax, 16 lanes per row; (j+q) rotation -> 2-way banks
    {
        const int q = tid >> 4, sub = tid & 15;
        float* row = s + (q << 10);
        float mx = -3.0e38f;
        #pragma unroll 4
        for (int j = 0; j < 64; ++j)
            mx = fmaxf(mx, row[sub + (((j + q) & 63) << 4)]);
        #pragma unroll
        for (int off = 8; off; off >>= 1) mx = fmaxf(mx, __shfl_xor(mx, off, 16));
        float sm = 0.f;
        #pragma unroll 4
        for (int j = 0; j < 64; ++j) {
            const int k = sub + (((j + q) & 63) << 4);
            const float e = __expf(row[k] - mx);
            row[k] = e;
            sm += e;
        }
        #pragma unroll
        for (int off = 8; off; off >>= 1) sm += __shfl_xor(sm, off, 16);
        const float inv = 1.0f / sm;
        #pragma unroll 4
        for (int j = 0; j < 64; ++j)
            row[sub + (((j + q) & 63) << 4)] *= inv;
    }

    // ---- row0 fix: global query 0; row 0 was normalized by lanes 0..15 of
    // this same wave, so no extra sync needed before the fix ----
    if (rt == 0 && tid < 16) {
        const float p0  = s[0];
        const float a00 = fminf(fmaxf(p0 + cls_bias[bh % 12], 0.f), 1.f);
        float actual = 0.f;
        for (int j = 0; j < 64; ++j) {
            const int k = tid + (j << 4);
            if (k) actual += s[k];
        }
        #pragma unroll
        for (int off = 8; off; off >>= 1) actual += __shfl_xor(actual, off, 16);
        const float mp = (1.0f - a00) / (actual + 1e-6f);
        for (int j = 0; j < 64; ++j) {
            const int k = tid + (j << 4);
            s[k] = (k == 0) ? a00 : fminf(fmaxf(s[k] * mp, 0.f), 1.f);
        }
    }
    __syncthreads();

    // ---- phase 3: write attn (output 1), coalesced float4 ----
    {
        float4* dst = (float4*)(attn + ((size_t)bh << 20) + ((size_t)q0 << 10));
        const float4* src = (const float4*)s;
        #pragma unroll
        for (int i = 0; i < 16; ++i)
            dst[tid + (i << 8)] = src[tid + (i << 8)];
    }
}

// ---------------------------------------------------------------------------
// O1 = attn @ V per (b,h): M=1024, K=1024, N=64. Tiled GEMM, 64x64 tile,
// Bk=16, 4x4 micro-tile, P transposed into LDS (stride 68 = 16B-aligned,
// 2-way banks). V read ONCE per block.
// grid = (16 m-tiles, 48 bh), 256 threads, 8.4 KB LDS.
// ---------------------------------------------------------------------------
__global__ __launch_bounds__(256)
void pv_gemm(const float* __restrict__ attn, const float* __restrict__ V,
             float* __restrict__ O1)
{
    __shared__ float Pt[16][68];   // [k][m], stride 272 B (17*16)
    __shared__ float Vt[16][64];   // [k][n]
    const int tid = threadIdx.x;
    const int bh  = blockIdx.y;
    const int m0  = blockIdx.x << 6;
    const int b   = bh / 12, h = bh - b * 12;
    const size_t bhoff = (size_t)bh << 16;
    const float* Pg = attn + ((size_t)bh << 20);

    const int pr = tid >> 2;            // 0..63  P stage row
    const int pk = (tid & 3) << 2;      // 0,4,8,12
    const int vk = tid >> 4;            // 0..15  V stage k
    const int vn = (tid & 15) << 2;     // n quad
    const int tx = tid & 15, ty = tid >> 4;

    float acc[4][4] = {};

    for (int k0 = 0; k0 < 1024; k0 += 16) {
        float4 pv4 = *(const float4*)(Pg + (size_t)(m0 + pr) * 1024 + k0 + pk);
        float4 vv4 = *(const float4*)(V + bhoff + (size_t)(k0 + vk) * 64 + vn);
        __syncthreads();
        Pt[pk+0][pr] = pv4.x; Pt[pk+1][pr] = pv4.y;
        Pt[pk+2][pr] = pv4.z; Pt[pk+3][pr] = pv4.w;
        *(float4*)&Vt[vk][vn] = vv4;
        __syncthreads();
        #pragma unroll
        for (int kk = 0; kk < 16; ++kk) {
            float4 a  = *(const float4*)&Pt[kk][ty << 2];
            float4 bv = *(const float4*)&Vt[kk][tx << 2];
            float av[4] = {a.x, a.y, a.z, a.w};
            float bb[4] = {bv.x, bv.y, bv.z, bv.w};
            #pragma unroll
            for (int i = 0; i < 4; ++i)
                #pragma unroll
                for (int j = 0; j < 4; ++j)
                    acc[i][j] = fmaf(av[i], bb[j], acc[i][j]);
        }
    }

    #pragma unroll
    for (int i = 0; i < 4; ++i) {
        float4 r = {acc[i][0], acc[i][1], acc[i][2], acc[i][3]};
        const int m = m0 + (ty << 2) + i;
        *(float4*)(O1 + ((size_t)(b * 1024 + m)) * 768 + (h << 6) + (tx << 2)) = r;
    }
}

extern "C" void kernel_launch(void* const* d_in, const int* in_sizes, int n_in,
                              void* d_out, int out_size, void* d_ws, size_t ws_size,
                              hipStream_t stream) {
    const float* x        = (const float*)d_in[0];
    const float* qkv_w    = (const float*)d_in[1];
    const float* qkv_b    = (const float*)d_in[2];
    const float* proj_w   = (const float*)d_in[3];
    const float* proj_b   = (const float*)d_in[4];
    const float* cls_bias = (const float*)d_in[5];

    float* out  = (float*)d_out;
    float* attn = out + OUT0_ELEMS;

    float* ws = (float*)d_ws;
    float* Q  = ws;                       // 12.6 MB (pre-scaled by 0.125)
    float* K  = Q  + (size_t)QKV_F32;     // 12.6 MB
    float* V  = K  + (size_t)QKV_F32;     // 12.6 MB
    float* O1 = V  + (size_t)QKV_F32;     // 12.6 MB

    // 1) qkv = x @ qkv_w.T + qkv_b -> Q(scaled)/K/V
    gemm128<1><<<dim3(18, 32), 256, 0, stream>>>(x, qkv_w, qkv_b, Q, K, V);
    // 2) attn = row0-fixed softmax(Q K^T)  (output 1)
    attn_scores<<<dim3(64, 48), 256, 0, stream>>>(Q, K, cls_bias, attn);
    // 3) O1 = attn @ V  (reads the just-written attn, L3-resident)
    pv_gemm<<<dim3(16, 48), 256, 0, stream>>>(attn, V, O1);
    // 4) out = O1 @ proj_w.T + proj_b  (output 0)
    gemm128<0><<<dim3(6, 32), 256, 0, stream>>>(O1, proj_w, proj_b, out, nullptr, nullptr);
}